// Round 4
// baseline (33.157 us; speedup 1.0000x reference)
//
#include <hip/hip_runtime.h>
#include <hip/hip_fp16.h>

// Problem constants (from reference setup_inputs)
constexpr int BAG       = 40;
constexpr int D         = 768;
constexpr int VOCAB     = 1276;
constexpr int AGE_DEPTH = 91;
constexpr int WROWS     = VOCAB + AGE_DEPTH;   // 1367

typedef float fx4 __attribute__((ext_vector_type(4)));   // native vector for NT stores

__device__ __forceinline__ __half2 u2h(uint u) {
    union { uint u; __half2 h; } v; v.u = u; return v.h;
}

// ---------------------------------------------------------------------------
// Pass 1: convert W (f32, [1367,768]) -> f16 table in workspace (RNE).
// f16 for these small values (|w| ~ 0.02*N(0,1)) has 4x less error than bf16
// and enables packed v_pk_add_f16 accumulation without unpacking.
// ---------------------------------------------------------------------------
__global__ __launch_bounds__(256) void convert_w_f16(
    const float* __restrict__ W, ushort* __restrict__ Wh, int n)
{
    const int i = (blockIdx.x * 256 + threadIdx.x) * 8;
    if (i + 8 > n) return;
    const float4 a = *reinterpret_cast<const float4*>(W + i);
    const float4 b = *reinterpret_cast<const float4*>(W + i + 4);
    const float v[8] = {a.x, a.y, a.z, a.w, b.x, b.y, b.z, b.w};
    ushort r[8];
    #pragma unroll
    for (int k = 0; k < 8; ++k) {
        __half h = __float2half(v[k]);   // RNE
        r[k] = *reinterpret_cast<ushort*>(&h);
    }
    uint4 packed;
    packed.x = (uint)r[0] | ((uint)r[1] << 16);
    packed.y = (uint)r[2] | ((uint)r[3] << 16);
    packed.z = (uint)r[4] | ((uint)r[5] << 16);
    packed.w = (uint)r[6] | ((uint)r[7] << 16);
    *reinterpret_cast<uint4*>(Wh + i) = packed;
}

// ---------------------------------------------------------------------------
// Pass 2: gather-sum with packed-f16 accumulate.
// Block: 192 threads = 2 rows x 96 threads, 8 f16 cols (16B) per thread.
// Per 16B gather: 4 v_pk_add_f16 (vs 16 VALU ops for bf16 unpack+f32 add).
// ---------------------------------------------------------------------------
__global__ __launch_bounds__(192, 6) void embedbag_f16_kernel(
    const int* __restrict__ word,    // [ROWS, BAG]
    const int* __restrict__ age,     // [ROWS]
    const __half* __restrict__ Wh,   // [WROWS, D] f16
    const float* __restrict__ bias,  // [D]
    float* __restrict__ out)         // [ROWS, D] f32
{
    const int tid  = threadIdx.x;
    const int sub  = tid / 96;            // 0..1  (row within block)
    const int lane = tid - sub * 96;      // 0..95
    const int row  = blockIdx.x * 2 + sub;
    const int c    = lane * 8;            // column start, 0..760

    const int* __restrict__ wrow = word + row * BAG;
    const __half* __restrict__ wp = Wh + c;

    const int aidx = VOCAB + age[row];    // issue early

    __half2 acc0 = u2h(0u), acc1 = u2h(0u), acc2 = u2h(0u), acc3 = u2h(0u);

    // First 8 indices
    int idx[8];
    {
        const int4 q0 = *reinterpret_cast<const int4*>(wrow);
        const int4 q1 = *reinterpret_cast<const int4*>(wrow + 4);
        idx[0]=q0.x; idx[1]=q0.y; idx[2]=q0.z; idx[3]=q0.w;
        idx[4]=q1.x; idx[5]=q1.y; idx[6]=q1.z; idx[7]=q1.w;
    }

    #pragma unroll
    for (int kb = 0; kb < 5; ++kb) {
        // Issue 8 gathers (in-flight together)
        uint4 g[8];
        #pragma unroll
        for (int u = 0; u < 8; ++u)
            g[u] = *reinterpret_cast<const uint4*>(wp + (size_t)idx[u] * D);

        // Prefetch next batch's indices while gathers are in flight
        int nxt[8];
        if (kb < 4) {
            const int4 q0 = *reinterpret_cast<const int4*>(wrow + 8 * kb + 8);
            const int4 q1 = *reinterpret_cast<const int4*>(wrow + 8 * kb + 12);
            nxt[0]=q0.x; nxt[1]=q0.y; nxt[2]=q0.z; nxt[3]=q0.w;
            nxt[4]=q1.x; nxt[5]=q1.y; nxt[6]=q1.z; nxt[7]=q1.w;
        }

        // Consume: packed f16 adds, no unpack
        #pragma unroll
        for (int u = 0; u < 8; ++u) {
            acc0 = __hadd2(acc0, u2h(g[u].x));
            acc1 = __hadd2(acc1, u2h(g[u].y));
            acc2 = __hadd2(acc2, u2h(g[u].z));
            acc3 = __hadd2(acc3, u2h(g[u].w));
        }

        if (kb < 4) {
            #pragma unroll
            for (int u = 0; u < 8; ++u) idx[u] = nxt[u];
        }
    }

    // Age row (41st gather)
    {
        const uint4 g = *reinterpret_cast<const uint4*>(wp + (size_t)aidx * D);
        acc0 = __hadd2(acc0, u2h(g.x));
        acc1 = __hadd2(acc1, u2h(g.y));
        acc2 = __hadd2(acc2, u2h(g.z));
        acc3 = __hadd2(acc3, u2h(g.w));
    }

    // Epilogue: f32 bias add, nontemporal store (keep W resident in L2)
    const float4 b0 = *reinterpret_cast<const float4*>(bias + c);
    const float4 b1 = *reinterpret_cast<const float4*>(bias + c + 4);
    fx4 o0 = { b0.x + __low2float(acc0), b0.y + __high2float(acc0),
               b0.z + __low2float(acc1), b0.w + __high2float(acc1) };
    fx4 o1 = { b1.x + __low2float(acc2), b1.y + __high2float(acc2),
               b1.z + __low2float(acc3), b1.w + __high2float(acc3) };
    float* op = out + (size_t)row * D + c;
    __builtin_nontemporal_store(o0, reinterpret_cast<fx4*>(op));
    __builtin_nontemporal_store(o1, reinterpret_cast<fx4*>(op + 4));
}

// ---------------------------------------------------------------------------
// Fallback (f32 direct gather) if workspace is too small for the f16 table.
// ---------------------------------------------------------------------------
__global__ __launch_bounds__(192) void embedbag_f32_kernel(
    const int* __restrict__ word, const int* __restrict__ age,
    const float* __restrict__ W, const float* __restrict__ bias,
    float* __restrict__ out)
{
    const int row = blockIdx.x;
    const int c   = threadIdx.x * 4;

    float4 acc = *reinterpret_cast<const float4*>(&bias[c]);
    const int* __restrict__ wrow = word + row * BAG;

    #pragma unroll 8
    for (int j = 0; j < BAG; ++j) {
        const int idx = wrow[j];
        const float4 v = *reinterpret_cast<const float4*>(&W[(size_t)idx * D + c]);
        acc.x += v.x; acc.y += v.y; acc.z += v.z; acc.w += v.w;
    }
    {
        const int idx = VOCAB + age[row];
        const float4 v = *reinterpret_cast<const float4*>(&W[(size_t)idx * D + c]);
        acc.x += v.x; acc.y += v.y; acc.z += v.z; acc.w += v.w;
    }
    *reinterpret_cast<float4*>(&out[(size_t)row * D + c]) = acc;
}

extern "C" void kernel_launch(void* const* d_in, const int* in_sizes, int n_in,
                              void* d_out, int out_size, void* d_ws, size_t ws_size,
                              hipStream_t stream) {
    const int* word   = (const int*)d_in[0];   // [B,S,BAG]
    const int* age    = (const int*)d_in[1];   // [B,S]
    const float* W    = (const float*)d_in[2]; // [WROWS, D]
    const float* bias = (const float*)d_in[3]; // [D]
    float* out        = (float*)d_out;         // [B,S,D]

    const int rows = in_sizes[1];              // B*S = 8192

    const size_t need = (size_t)WROWS * D * sizeof(ushort);  // 2.1 MB
    if (ws_size >= need) {
        ushort* Wh = (ushort*)d_ws;
        const int n = WROWS * D;
        convert_w_f16<<<(n / 8 + 255) / 256, 256, 0, stream>>>(W, Wh, n);
        embedbag_f16_kernel<<<rows / 2, 192, 0, stream>>>(
            word, age, (const __half*)Wh, bias, out);
    } else {
        embedbag_f32_kernel<<<rows, D / 4, 0, stream>>>(word, age, W, bias, out);
    }
}

// Round 5
// 26.742 us; speedup vs baseline: 1.2398x; 1.2398x over previous
//
#include <hip/hip_runtime.h>
#include <hip/hip_fp16.h>

// Problem constants (from reference setup_inputs)
constexpr int BAG       = 40;
constexpr int D         = 768;
constexpr int VOCAB     = 1276;
constexpr int AGE_DEPTH = 91;
constexpr int WROWS     = VOCAB + AGE_DEPTH;   // 1367

constexpr int COLS   = 32;          // f16 columns staged per block
constexpr int NSLICE = D / COLS;    // 24 column slices
constexpr int RPB    = 256;         // rows per block (1 row per 4-lane group)
constexpr int TPB    = 1024;        // 16 waves; LDS 87.5KB -> 1 block/CU
constexpr int NCHUNK = COLS / 8;    // 4 chunks of 8 f16 (16B) per row
constexpr int LDSU   = NCHUNK * WROWS;  // 5468 uint4 = 87,488 B

typedef float fx4 __attribute__((ext_vector_type(4)));

__device__ __forceinline__ __half2 u2h(uint u) {
    union { uint u; __half2 h; } v; v.u = u; return v.h;
}
__device__ __forceinline__ ushort f2h(float f) {
    __half h = __float2half(f);     // RNE
    return *reinterpret_cast<ushort*>(&h);
}

// ---------------------------------------------------------------------------
// One kernel: stage f32 W column-slice -> f16 in LDS, then gather-sum 41
// table rows per output row from LDS. No workspace, no convert pass.
// Grid: (rowblocks, NSLICE). Block: 1024 thr = 256 rows x 4 chunk-lanes.
// LDS layout: chunk-interleaved, entry (c,r) at lds4[c*WROWS + r] so a
// wave's 16 random rows spread across banks (start bank = (28c+4r)%32).
// ---------------------------------------------------------------------------
__global__ __launch_bounds__(TPB) void embed_lds_kernel(
    const int* __restrict__ word,    // [ROWS, BAG]
    const int* __restrict__ age,     // [ROWS]
    const float* __restrict__ W,     // [WROWS, D] f32
    const float* __restrict__ bias,  // [D]
    float* __restrict__ out)         // [ROWS, D] f32
{
    __shared__ uint4 lds4[LDSU];

    const int rb    = blockIdx.x;          // row-block
    const int slice = blockIdx.y;          // column slice
    const int c0    = slice * COLS;

    // ---- stage: W[r, c0:c0+32] f32 -> f16, chunk-interleaved in LDS ----
    for (int s = threadIdx.x; s < LDSU; s += TPB) {
        const int r = s >> 2;              // table row
        const int u = s & 3;               // chunk (8 cols)
        const float* src = W + (size_t)r * D + c0 + u * 8;
        const float4 a = *reinterpret_cast<const float4*>(src);
        const float4 b = *reinterpret_cast<const float4*>(src + 4);
        uint4 p;
        p.x = (uint)f2h(a.x) | ((uint)f2h(a.y) << 16);
        p.y = (uint)f2h(a.z) | ((uint)f2h(a.w) << 16);
        p.z = (uint)f2h(b.x) | ((uint)f2h(b.y) << 16);
        p.w = (uint)f2h(b.z) | ((uint)f2h(b.w) << 16);
        lds4[u * WROWS + r] = p;
    }

    // ---- load this thread's row indices while staging loads are in flight
    const int t     = threadIdx.x;
    const int chunk = t & 3;               // which 8-col chunk of the slice
    const int rloc  = t >> 2;              // 0..255
    const int row   = rb * RPB + rloc;

    const int* __restrict__ wrow = word + row * BAG;   // 160B-aligned
    int idx[BAG];
    #pragma unroll
    for (int j = 0; j < BAG; j += 4) {
        const int4 q = *reinterpret_cast<const int4*>(wrow + j);
        idx[j] = q.x; idx[j + 1] = q.y; idx[j + 2] = q.z; idx[j + 3] = q.w;
    }
    const int aidx = VOCAB + age[row];

    __syncthreads();

    // ---- gather 41 rows from LDS, packed-f16 accumulate ----
    const uint4* __restrict__ lp = lds4 + chunk * WROWS;

    __half2 acc0 = u2h(0u), acc1 = u2h(0u), acc2 = u2h(0u), acc3 = u2h(0u);
    #pragma unroll
    for (int j = 0; j < BAG; ++j) {
        const uint4 g = lp[idx[j]];        // ds_read_b128
        acc0 = __hadd2(acc0, u2h(g.x));
        acc1 = __hadd2(acc1, u2h(g.y));
        acc2 = __hadd2(acc2, u2h(g.z));
        acc3 = __hadd2(acc3, u2h(g.w));
    }
    {
        const uint4 g = lp[aidx];
        acc0 = __hadd2(acc0, u2h(g.x));
        acc1 = __hadd2(acc1, u2h(g.y));
        acc2 = __hadd2(acc2, u2h(g.z));
        acc3 = __hadd2(acc3, u2h(g.w));
    }

    // ---- epilogue: f32 bias add, nontemporal 32B store ----
    const float* bp = bias + c0 + chunk * 8;
    const float4 b0 = *reinterpret_cast<const float4*>(bp);
    const float4 b1 = *reinterpret_cast<const float4*>(bp + 4);
    fx4 o0 = { b0.x + __low2float(acc0), b0.y + __high2float(acc0),
               b0.z + __low2float(acc1), b0.w + __high2float(acc1) };
    fx4 o1 = { b1.x + __low2float(acc2), b1.y + __high2float(acc2),
               b1.z + __low2float(acc3), b1.w + __high2float(acc3) };
    float* op = out + (size_t)row * D + c0 + chunk * 8;
    __builtin_nontemporal_store(o0, reinterpret_cast<fx4*>(op));
    __builtin_nontemporal_store(o1, reinterpret_cast<fx4*>(op + 4));
}

// ---------------------------------------------------------------------------
// Fallback (f32 direct gather) if rows isn't a multiple of RPB.
// ---------------------------------------------------------------------------
__global__ __launch_bounds__(192) void embedbag_f32_kernel(
    const int* __restrict__ word, const int* __restrict__ age,
    const float* __restrict__ W, const float* __restrict__ bias,
    float* __restrict__ out)
{
    const int row = blockIdx.x;
    const int c   = threadIdx.x * 4;

    float4 acc = *reinterpret_cast<const float4*>(&bias[c]);
    const int* __restrict__ wrow = word + row * BAG;

    #pragma unroll 8
    for (int j = 0; j < BAG; ++j) {
        const int idx = wrow[j];
        const float4 v = *reinterpret_cast<const float4*>(&W[(size_t)idx * D + c]);
        acc.x += v.x; acc.y += v.y; acc.z += v.z; acc.w += v.w;
    }
    {
        const int idx = VOCAB + age[row];
        const float4 v = *reinterpret_cast<const float4*>(&W[(size_t)idx * D + c]);
        acc.x += v.x; acc.y += v.y; acc.z += v.z; acc.w += v.w;
    }
    *reinterpret_cast<float4*>(&out[(size_t)row * D + c]) = acc;
}

extern "C" void kernel_launch(void* const* d_in, const int* in_sizes, int n_in,
                              void* d_out, int out_size, void* d_ws, size_t ws_size,
                              hipStream_t stream) {
    const int* word   = (const int*)d_in[0];   // [B,S,BAG]
    const int* age    = (const int*)d_in[1];   // [B,S]
    const float* W    = (const float*)d_in[2]; // [WROWS, D]
    const float* bias = (const float*)d_in[3]; // [D]
    float* out        = (float*)d_out;         // [B,S,D]

    const int rows = in_sizes[1];              // B*S = 8192

    if (rows % RPB == 0) {
        dim3 grid(rows / RPB, NSLICE);         // (32, 24) = 768 blocks, 3/CU
        embed_lds_kernel<<<grid, TPB, 0, stream>>>(word, age, W, bias, out);
    } else {
        embedbag_f32_kernel<<<rows, D / 4, 0, stream>>>(word, age, W, bias, out);
    }
}